// Round 11
// baseline (228.664 us; speedup 1.0000x reference)
//
#include <hip/hip_runtime.h>
#include <stdint.h>

// Pipeline: detect dtype -> cast inputs to bf16 -> transpose weights ->
//   GEMM1(x @ w_attn^T, scatter Q*scale*log2e / K+rel / V^T) -> flash attention
//   (swapped-QK^T lane-local softmax, log2-domain) -> GEMM2 (+b_proj) -> out
// R11: gemm_qkv moves to 256x128 tile (L2-BW-bound fix: FLOP/B 64->87,
// L2 traffic 453->339 MB). 3-buf counted-vmcnt schedule kept (now vmcnt(6)).

typedef __attribute__((ext_vector_type(8))) short short8;
typedef __attribute__((ext_vector_type(4))) float f32x4;
typedef __attribute__((ext_vector_type(4))) unsigned short ushort4v;

#define DEV static __device__ __forceinline__

DEV float bf2f(unsigned short u) {
    union { unsigned int u; float f; } v; v.u = ((unsigned int)u) << 16; return v.f;
}
DEV unsigned short f2bf(float f) {
    union { float f; unsigned int u; } v; v.f = f;
    unsigned int u = v.u;
    return (unsigned short)((u + 0x7fffu + ((u >> 16) & 1u)) >> 16);
}

typedef const __attribute__((address_space(1))) void* gas_ptr;
typedef __attribute__((address_space(3))) void* las_ptr;
DEV void glds16(const void* g, void* l) {
    __builtin_amdgcn_global_load_lds((gas_ptr)g, (las_ptr)l, 16, 0, 0);
}

// ---------------- dtype detector ----------------
__global__ void detect_dtype(const unsigned int* __restrict__ w, int* __restrict__ flag) {
    __shared__ int cnt;
    if (threadIdx.x == 0) cnt = 0;
    __syncthreads();
    int c = 0;
    for (int i = threadIdx.x; i < 8192; i += 256) {
        unsigned int b1 = (w[i] >> 8) & 0x7F;
        c += (b1 >= 0x38 && b1 <= 0x3E) ? 1 : 0;
    }
    atomicAdd(&cnt, c);
    __syncthreads();
    if (threadIdx.x == 0) *flag = (cnt > 4096) ? 1 : 0;  // 1 = bf16 inputs
}

// ---------------- casts ----------------
__global__ __launch_bounds__(256) void cast_x(
    const void* __restrict__ x, unsigned short* __restrict__ xo,
    const int* __restrict__ flag)
{
    int i = (blockIdx.x * 256 + threadIdx.x) * 4;
    if (*flag) {
        *(ushort4v*)(xo + i) = *(const ushort4v*)((const unsigned short*)x + i);
    } else {
        f32x4 v = *(const f32x4*)((const float*)x + i);
        ushort4v o;
#pragma unroll
        for (int j = 0; j < 4; ++j) o[j] = f2bf(v[j]);
        *(ushort4v*)(xo + i) = o;
    }
}

__global__ __launch_bounds__(256) void cast_small(
    const void* __restrict__ rel, const void* __restrict__ ba, const void* __restrict__ bp,
    unsigned short* __restrict__ rel_o, unsigned short* __restrict__ ba_o,
    unsigned short* __restrict__ bp_o, const int* __restrict__ flag)
{
    int i = blockIdx.x * 256 + threadIdx.x;
    if (i >= 134080) return;
    int isbf = *flag;
    const void* src; unsigned short* dst; int off;
    if (i < 131008)      { src = rel; dst = rel_o; off = i; }
    else if (i < 133312) { src = ba;  dst = ba_o;  off = i - 131008; }
    else                 { src = bp;  dst = bp_o;  off = i - 133312; }
    dst[off] = isbf ? ((const unsigned short*)src)[off]
                    : f2bf(((const float*)src)[off]);
}

// ---------------- weight transpose (either dtype in, bf16 out), 64x64 tiles ----
__global__ __launch_bounds__(256) void transpose_w(
    const void* __restrict__ in, unsigned short* __restrict__ out,
    int R, int C, const int* __restrict__ flag)
{
    __shared__ unsigned short tile[64][66];
    const int t = threadIdx.x;
    const int cb = blockIdx.x * 64;
    const int rb = blockIdx.y * 64;
    if (*flag) {
        const unsigned short* inp = (const unsigned short*)in;
        const int c8 = (t & 7) * 8;
        const int r = t >> 3;
#pragma unroll
        for (int p = 0; p < 2; ++p) {
            int rr = r + p * 32;
            short8 v = *(const short8*)(inp + (size_t)(rb + rr) * C + cb + c8);
#pragma unroll
            for (int i = 0; i < 8; ++i) tile[rr][c8 + i] = (unsigned short)v[i];
        }
    } else {
        const float* inp = (const float*)in;
        const int c4 = (t & 15) * 4;
        const int r = t >> 4;
#pragma unroll
        for (int p = 0; p < 4; ++p) {
            int rr = r + p * 16;
            f32x4 v = *(const f32x4*)(inp + (size_t)(rb + rr) * C + cb + c4);
#pragma unroll
            for (int i = 0; i < 4; ++i) tile[rr][c4 + i] = f2bf(v[i]);
        }
    }
    __syncthreads();
    {
        const int c8 = (t & 7) * 8;
        const int r = t >> 3;
#pragma unroll
        for (int p = 0; p < 2; ++p) {
            int oc = r + p * 32;
            short8 v;
#pragma unroll
            for (int i = 0; i < 8; ++i) v[i] = (short)tile[c8 + i][oc];
            *(short8*)(out + (size_t)(cb + oc) * R + rb + c8) = v;
        }
    }
}

// -- GEMM1 skeleton: 256x128 tile, BK=32, 4 waves (wave = 64 M-rows x 128 N) --
// 3-buf + counted vmcnt(6): per step t, wait vmcnt(6) [tile t landed, t+1 in
// flight] -> s_barrier -> stage(t+2) -> ds_read -> 32 MFMA.
#define G1_STAGE(kk, sl)                                                         \
    glds16(Ab + (size_t)ra0 * 768 + (kk) + oa0, (char*)Abuf[sl] + la0);          \
    glds16(Ab + (size_t)ra1 * 768 + (kk) + oa1, (char*)Abuf[sl] + la1);          \
    glds16(Ab + (size_t)ra2 * 768 + (kk) + oa2, (char*)Abuf[sl] + la2);          \
    glds16(Ab + (size_t)ra3 * 768 + (kk) + oa3, (char*)Abuf[sl] + la3);          \
    glds16(Bb + (size_t)rb0 * 768 + (kk) + ob0, (char*)Bbuf[sl] + lb0);          \
    glds16(Bb + (size_t)rb1 * 768 + (kk) + ob1, (char*)Bbuf[sl] + lb1);

// GEMM1: epilogue scatters q (scale*log2e folded), k (+rel), v (transposed)
__global__ __launch_bounds__(256) void gemm_qkv(
    const unsigned short* __restrict__ A,
    const unsigned short* __restrict__ Bt,
    const unsigned short* __restrict__ bias,
    const unsigned short* __restrict__ rel,
    unsigned short* __restrict__ q_ws,
    unsigned short* __restrict__ k_ws,
    unsigned short* __restrict__ v_ws)
{
    __shared__ __align__(16) unsigned short Abuf[3][256 * 32];
    __shared__ __align__(16) unsigned short Bbuf[3][128 * 32];
    const int t = threadIdx.x;
    const int wave = t >> 6, lane = t & 63;
    const int lo = lane & 15, hi = lane >> 4;
    const int bm = blockIdx.x * 256;
    const int bn = blockIdx.y * 128;
    // staging: linear LDS dest (chunk c at (t+256c)*16), pre-swizzled source
    int ra[4], oa[4], la[4];
#pragma unroll
    for (int c = 0; c < 4; ++c) {
        int L = (t + 256 * c) << 4;
        int S = L ^ (((L >> 7) & 3) << 4);
        ra[c] = S >> 6; oa[c] = (S & 63) >> 1;
        la[c] = ((wave * 64) + c * 256) << 4;
    }
    const int ra0 = ra[0], ra1 = ra[1], ra2 = ra[2], ra3 = ra[3];
    const int oa0 = oa[0], oa1 = oa[1], oa2 = oa[2], oa3 = oa[3];
    const int la0 = la[0], la1 = la[1], la2 = la[2], la3 = la[3];
    int rb_[2], ob_[2], lb_[2];
#pragma unroll
    for (int c = 0; c < 2; ++c) {
        int L = (t + 256 * c) << 4;
        int S = L ^ (((L >> 7) & 3) << 4);
        rb_[c] = S >> 6; ob_[c] = (S & 63) >> 1;
        lb_[c] = ((wave * 64) + c * 256) << 4;
    }
    const int rb0 = rb_[0], rb1 = rb_[1];
    const int ob0 = ob_[0], ob1 = ob_[1];
    const int lb0 = lb_[0], lb1 = lb_[1];
    const unsigned short* Ab = A + (size_t)bm * 768;
    const unsigned short* Bb = Bt + (size_t)bn * 768;
    int aoff[4]; int boff[8];
#pragma unroll
    for (int m = 0; m < 4; ++m) {
        int Pa = ((wave * 64 + m * 16 + lo) << 6) + (hi << 4);
        aoff[m] = Pa ^ (((Pa >> 7) & 3) << 4);
    }
#pragma unroll
    for (int n = 0; n < 8; ++n) {
        int Pb = ((n * 16 + lo) << 6) + (hi << 4);
        boff[n] = Pb ^ (((Pb >> 7) & 3) << 4);
    }
    f32x4 acc[4][8];
#pragma unroll
    for (int m = 0; m < 4; ++m)
#pragma unroll
        for (int n = 0; n < 8; ++n) acc[m][n] = (f32x4){0.f, 0.f, 0.f, 0.f};
    G1_STAGE(0, 0)
    G1_STAGE(32, 1)
#pragma unroll
    for (int kt_ = 0; kt_ < 24; ++kt_) {
        if (kt_ < 23) { asm volatile("s_waitcnt vmcnt(6)" ::: "memory"); }
        else          { asm volatile("s_waitcnt vmcnt(0)" ::: "memory"); }
        __builtin_amdgcn_s_barrier();
        if (kt_ + 2 < 24) { G1_STAGE((kt_ + 2) * 32, (kt_ + 2) % 3) }
        const int cur_ = kt_ % 3;
        short8 af[4], bfv[8];
#pragma unroll
        for (int m = 0; m < 4; ++m)
            af[m] = *(const short8*)((const char*)Abuf[cur_] + aoff[m]);
#pragma unroll
        for (int n = 0; n < 8; ++n)
            bfv[n] = *(const short8*)((const char*)Bbuf[cur_] + boff[n]);
#pragma unroll
        for (int m = 0; m < 4; ++m)
#pragma unroll
            for (int n = 0; n < 8; ++n)
                acc[m][n] = __builtin_amdgcn_mfma_f32_16x16x32_bf16(
                    af[m], bfv[n], acc[m][n], 0, 0, 0);
    }
    const int gm0 = bm + wave * 64 + hi * 4;
    const float QSCALE = 0.125f * 1.44269504f;  // fold log2e
#pragma unroll
    for (int m = 0; m < 4; ++m) {
        int gm = gm0 + m * 16;
        int b_ = gm >> 10;
        int tt = gm & 1023;
#pragma unroll
        for (int n = 0; n < 8; ++n) {
            int col = bn + n * 16 + lo;
            float bs = bf2f(bias[col]);
            if (col < 768) {
                int h = col >> 6, d = col & 63;
                size_t base = (((size_t)b_ * 12 + h) * 1024 + tt) * 64 + d;
#pragma unroll
                for (int j = 0; j < 4; ++j)
                    q_ws[base + (size_t)j * 64] = f2bf((acc[m][n][j] + bs) * QSCALE);
            } else if (col < 1536) {
                int h = (col - 768) >> 6, d = col & 63;
                size_t base = (((size_t)b_ * 12 + h) * 1024 + tt) * 64 + d;
#pragma unroll
                for (int j = 0; j < 4; ++j) {
                    int trow = tt + j;
                    float rv = (trow > 0) ? bf2f(rel[(size_t)(trow - 1) * 64 + d]) : 0.f;
                    k_ws[base + (size_t)j * 64] = f2bf(acc[m][n][j] + bs + rv);
                }
            } else {
                int h = (col - 1536) >> 6, d = col & 63;
                size_t vb = (((size_t)b_ * 12 + h) * 64 + d) * 1024 + tt;
                ushort4v pk;
#pragma unroll
                for (int j = 0; j < 4; ++j) pk[j] = f2bf(acc[m][n][j] + bs);
                *(ushort4v*)(v_ws + vb) = pk;
            }
        }
    }
}

// -- GEMM2 skeleton (128x128, R10 3-buf vmcnt(4) macro) ------------------------
#define GEMM_STAGE(kk, sl)                                                       \
    glds16(Ab + (size_t)r0 * 768 + (kk) + o0, (char*)Abuf[sl] + lof0);           \
    glds16(Ab + (size_t)r1 * 768 + (kk) + o1, (char*)Abuf[sl] + lof1);           \
    glds16(Bb + (size_t)r0 * 768 + (kk) + o0, (char*)Bbuf[sl] + lof0);           \
    glds16(Bb + (size_t)r1 * 768 + (kk) + o1, (char*)Bbuf[sl] + lof1);

__global__ __launch_bounds__(256) void gemm_proj(
    const unsigned short* __restrict__ A,
    const unsigned short* __restrict__ Bt,
    const unsigned short* __restrict__ bias,
    const int* __restrict__ flag,
    void* __restrict__ outv)
{
    __shared__ __align__(16) unsigned short Abuf[3][128 * 32];
    __shared__ __align__(16) unsigned short Bbuf[3][128 * 32];
    const int t = threadIdx.x;
    const int wave = t >> 6, lane = t & 63;
    const int lo = lane & 15, hi = lane >> 4;
    const int wr = wave >> 1, wc = wave & 1;
    const int bm = blockIdx.x * 128;
    const int bn = blockIdx.y * 128;
    int L0 = t << 4, L1 = (t + 256) << 4;
    int S0 = L0 ^ (((L0 >> 7) & 3) << 4);
    int S1 = L1 ^ (((L1 >> 7) & 3) << 4);
    int r0 = S0 >> 6, o0 = (S0 & 63) >> 1;
    int r1 = S1 >> 6, o1 = (S1 & 63) >> 1;
    const unsigned short* Ab = A + (size_t)bm * 768;
    const unsigned short* Bb = Bt + (size_t)bn * 768;
    const int lof0 = (wave * 64) << 4;
    const int lof1 = (256 + wave * 64) << 4;
    int aoff[4]; int boff[4];
#pragma unroll
    for (int m = 0; m < 4; ++m) {
        int Pa = ((wr * 64 + m * 16 + lo) << 6) + (hi << 4);
        aoff[m] = Pa ^ (((Pa >> 7) & 3) << 4);
        int Pb = ((wc * 64 + m * 16 + lo) << 6) + (hi << 4);
        boff[m] = Pb ^ (((Pb >> 7) & 3) << 4);
    }
    f32x4 acc[4][4];
#pragma unroll
    for (int m = 0; m < 4; ++m)
#pragma unroll
        for (int n = 0; n < 4; ++n) acc[m][n] = (f32x4){0.f, 0.f, 0.f, 0.f};
    GEMM_STAGE(0, 0)
    GEMM_STAGE(32, 1)
#pragma unroll
    for (int kt_ = 0; kt_ < 24; ++kt_) {
        if (kt_ < 23) { asm volatile("s_waitcnt vmcnt(4)" ::: "memory"); }
        else          { asm volatile("s_waitcnt vmcnt(0)" ::: "memory"); }
        __builtin_amdgcn_s_barrier();
        if (kt_ + 2 < 24) { GEMM_STAGE((kt_ + 2) * 32, (kt_ + 2) % 3) }
        const int cur_ = kt_ % 3;
        short8 af[4], bfv[4];
#pragma unroll
        for (int m = 0; m < 4; ++m)
            af[m] = *(const short8*)((const char*)Abuf[cur_] + aoff[m]);
#pragma unroll
        for (int n = 0; n < 4; ++n)
            bfv[n] = *(const short8*)((const char*)Bbuf[cur_] + boff[n]);
#pragma unroll
        for (int m = 0; m < 4; ++m)
#pragma unroll
            for (int n = 0; n < 4; ++n)
                acc[m][n] = __builtin_amdgcn_mfma_f32_16x16x32_bf16(
                    af[m], bfv[n], acc[m][n], 0, 0, 0);
    }
    const int isbf = *flag;
    const int gm0 = bm + wr * 64 + hi * 4;
#pragma unroll
    for (int m = 0; m < 4; ++m) {
        int gm = gm0 + m * 16;
#pragma unroll
        for (int n = 0; n < 4; ++n) {
            int col = bn + wc * 64 + n * 16 + lo;
            float bs = bf2f(bias[col]);
#pragma unroll
            for (int j = 0; j < 4; ++j) {
                float v = acc[m][n][j] + bs;
                if (isbf)
                    ((unsigned short*)outv)[(size_t)(gm + j) * 768 + col] = f2bf(v);
                else
                    ((float*)outv)[(size_t)(gm + j) * 768 + col] = v;
            }
        }
    }
}

// ---------------- flash attention (v6: swapped QK^T, lane-local softmax) ------
__global__ __launch_bounds__(256) void attn_fused(
    const unsigned short* __restrict__ q_ws,
    const unsigned short* __restrict__ k_ws,
    const unsigned short* __restrict__ v_ws,
    unsigned short* __restrict__ att)
{
    __shared__ __align__(16) unsigned short Kbuf[2][64 * 64];
    __shared__ __align__(16) unsigned short Vbuf[2][64 * 64];
    __shared__ __align__(16) unsigned short Pbuf[4][16 * 64];
    const int t = threadIdx.x;
    const int wave = t >> 6, lane = t & 63;
    const int lo = lane & 15, hi = lane >> 4;
    const int gid = blockIdx.x;
    const int xcd = gid & 7;
    const int c = gid >> 3;            // 0..95
    const int bh = xcd * 12 + (c % 12);
    const int pairIdx = c / 12;        // 0..7
    const int b_ = bh / 12, h = bh % 12;
    const size_t base = (size_t)bh * (1024 * 64);
    const unsigned short* Kb = k_ws + base;
    const unsigned short* Vb = v_ws + base;
    const float DEFER_THR = 11.5f;     // ~8 nats in log2 units

    int L0 = t << 4, L1 = (t + 256) << 4;
    int S0 = L0 ^ (((L0 >> 7) & 7) << 4);
    int S1 = L1 ^ (((L1 >> 7) & 7) << 4);
    int r0 = S0 >> 7, o0 = (S0 & 127) >> 1;
    int r1 = S1 >> 7, o1 = (S1 & 127) >> 1;
    const int lof0 = (wave * 64) << 4;
    const int lof1 = (256 + wave * 64) << 4;

    int koff[4][2];
#pragma unroll
    for (int nt = 0; nt < 4; ++nt)
#pragma unroll
        for (int kc = 0; kc < 2; ++kc) {
            int P = ((nt * 16 + lo) << 7) + (kc << 6) + (hi << 4);
            koff[nt][kc] = P ^ (((P >> 7) & 7) << 4);
        }
    int poffR[2];
#pragma unroll
    for (int kc = 0; kc < 2; ++kc) {
        int P = (lo << 7) + (kc << 6) + (hi << 4);
        poffR[kc] = P ^ (((P >> 7) & 7) << 4);
    }
    int poffW[4][4];
#pragma unroll
    for (int nt = 0; nt < 4; ++nt)
#pragma unroll
        for (int j = 0; j < 4; ++j) {
            int P = (lo << 7) + ((nt * 16 + hi * 4 + j) << 1);
            poffW[nt][j] = P ^ ((lo & 7) << 4);
        }
    char* pb = (char*)&Pbuf[wave][0];

#pragma unroll 1
    for (int sel = 0; sel < 2; ++sel) {
        const int qt = sel ? pairIdx : (15 - pairIdx);
        const int q0w = qt * 64 + wave * 16;
        const int qrow = q0w + lo;     // this lane's q-row

        short8 qf[2];
#pragma unroll
        for (int kc = 0; kc < 2; ++kc)
            qf[kc] = *(const short8*)(q_ws + base +
                (size_t)(q0w + lo) * 64 + kc * 32 + hi * 8);

        f32x4 o[4];
        float mrun = -1e30f, lrun = 0.f;
#pragma unroll
        for (int nt = 0; nt < 4; ++nt) o[nt] = (f32x4){0.f, 0.f, 0.f, 0.f};

        if (sel) __syncthreads();
        glds16(Kb + (size_t)r0 * 64 + o0, (char*)Kbuf[0] + lof0);
        glds16(Kb + (size_t)r1 * 64 + o1, (char*)Kbuf[0] + lof1);
        glds16(Vb + (size_t)r0 * 1024 + o0, (char*)Vbuf[0] + lof0);
        glds16(Vb + (size_t)r1 * 1024 + o1, (char*)Vbuf[0] + lof1);

        int cur = 0;
        const int nkt = qt + 1;
        for (int kt = 0; kt < nkt; ++kt) {
            __syncthreads();  // staging of tile kt complete
            if (kt + 1 < nkt) {
                const int kn = (kt + 1) * 64;
                glds16(Kb + (size_t)(kn + r0) * 64 + o0, (char*)Kbuf[cur ^ 1] + lof0);
                glds16(Kb + (size_t)(kn + r1) * 64 + o1, (char*)Kbuf[cur ^ 1] + lof1);
                glds16(Vb + (size_t)r0 * 1024 + kn + o0, (char*)Vbuf[cur ^ 1] + lof0);
                glds16(Vb + (size_t)r1 * 1024 + kn + o1, (char*)Vbuf[cur ^ 1] + lof1);
            }
            const int kv0 = kt * 64;
            const char* Kc = (const char*)Kbuf[cur];
            const char* Vc = (const char*)Vbuf[cur];

            short8 kf[4][2];
#pragma unroll
            for (int nt = 0; nt < 4; ++nt)
#pragma unroll
                for (int kc = 0; kc < 2; ++kc)
                    kf[nt][kc] = *(const short8*)(Kc + koff[nt][kc]);
            // swapped: A=K, B=Q -> sc[nt] col=q(lo), rows=kv(hi*4+j)
            f32x4 sc[4];
            __builtin_amdgcn_s_setprio(1);
#pragma unroll
            for (int nt = 0; nt < 4; ++nt) {
                f32x4 z = (f32x4){0.f, 0.f, 0.f, 0.f};
                z = __builtin_amdgcn_mfma_f32_16x16x32_bf16(kf[nt][0], qf[0], z, 0, 0, 0);
                z = __builtin_amdgcn_mfma_f32_16x16x32_bf16(kf[nt][1], qf[1], z, 0, 0, 0);
                sc[nt] = z;
            }
            __builtin_amdgcn_s_setprio(0);
            if (kv0 + 63 > q0w) {
#pragma unroll
                for (int nt = 0; nt < 4; ++nt)
#pragma unroll
                    for (int j = 0; j < 4; ++j) {
                        int kc_ = kv0 + nt * 16 + hi * 4 + j;
                        if (kc_ > qrow) sc[nt][j] = -1e30f;
                    }
            }
            // lane-local row max (15 VALU) + 2 shfl across hi-groups
            float m0;
            {
                float a0 = fmaxf(fmaxf(sc[0][0], sc[0][1]), fmaxf(sc[0][2], sc[0][3]));
                float a1 = fmaxf(fmaxf(sc[1][0], sc[1][1]), fmaxf(sc[1][2], sc[1][3]));
                float a2 = fmaxf(fmaxf(sc[2][0], sc[2][1]), fmaxf(sc[2][2], sc[2][3]));
                float a3 = fmaxf(fmaxf(sc[3][0], sc[3][1]), fmaxf(sc[3][2], sc[3][3]));
                m0 = fmaxf(fmaxf(a0, a1), fmaxf(a2, a3));
            }
            m0 = fmaxf(m0, __shfl_xor(m0, 16));
            m0 = fmaxf(m0, __shfl_xor(m0, 32));
            // defer-max rescale
            if (__any(m0 > mrun + DEFER_THR)) {
                float nm = fmaxf(mrun, m0);
                float corr = __builtin_amdgcn_exp2f(mrun - nm);
                mrun = nm;
                lrun *= corr;
#pragma unroll
                for (int j = 0; j < 4; ++j) {
                    float cj = __shfl(corr, hi * 4 + j);
#pragma unroll
                    for (int nt = 0; nt < 4; ++nt) o[nt][j] *= cj;
                }
            }
            // exp2 + lane-local sum + 2 shfl
            float rs = 0.f;
#pragma unroll
            for (int nt = 0; nt < 4; ++nt)
#pragma unroll
                for (int j = 0; j < 4; ++j) {
                    float p = __builtin_amdgcn_exp2f(sc[nt][j] - mrun);
                    sc[nt][j] = p;
                    rs += p;
                }
            rs += __shfl_xor(rs, 16);
            rs += __shfl_xor(rs, 32);
            lrun += rs;
            // V fragments (hoisted)
            short8 vf[4][2];
#pragma unroll
            for (int nt = 0; nt < 4; ++nt)
#pragma unroll
                for (int kc2 = 0; kc2 < 2; ++kc2)
                    vf[nt][kc2] = *(const short8*)(Vc + koff[nt][kc2]);
            // P -> LDS (row = lo = q-row)
#pragma unroll
            for (int nt = 0; nt < 4; ++nt)
#pragma unroll
                for (int j = 0; j < 4; ++j)
                    *(unsigned short*)(pb + poffW[nt][j]) = f2bf(sc[nt][j]);
            // PV
#pragma unroll
            for (int kc2 = 0; kc2 < 2; ++kc2) {
                short8 pf = *(const short8*)(pb + poffR[kc2]);
                __builtin_amdgcn_s_setprio(1);
#pragma unroll
                for (int nt = 0; nt < 4; ++nt)
                    o[nt] = __builtin_amdgcn_mfma_f32_16x16x32_bf16(pf, vf[nt][kc2], o[nt], 0, 0, 0);
                __builtin_amdgcn_s_setprio(0);
            }
            cur ^= 1;
        }
        // epilogue: lrun for row hi*4+j lives at lane (hi*4+j)
#pragma unroll
        for (int j = 0; j < 4; ++j) {
            float lj = __shfl(lrun, hi * 4 + j);
            float inv = 1.f / lj;
            int tt = q0w + hi * 4 + j;
#pragma unroll
            for (int nt = 0; nt < 4; ++nt)
                att[((size_t)(b_ * 1024 + tt)) * 768 + h * 64 + nt * 16 + lo] =
                    f2bf(o[nt][j] * inv);
        }
    }
}

extern "C" void kernel_launch(void* const* d_in, const int* in_sizes, int n_in,
                              void* d_out, int out_size, void* d_ws, size_t ws_size,
                              hipStream_t stream) {
    const void* x      = d_in[0];
    const void* w_attn = d_in[1];
    const void* b_attn = d_in[2];
    const void* w_proj = d_in[3];
    const void* b_proj = d_in[4];
    const void* rel    = d_in[5];
    char* ws = (char*)d_ws;
    int*            flag = (int*)(ws + 0);
    unsigned short* wTa  = (unsigned short*)(ws + 4096);
    unsigned short* wTp  = (unsigned short*)(ws + 3543040);
    unsigned short* x_bf = (unsigned short*)(ws + 4722688);
    unsigned short* relb = (unsigned short*)(ws + 17305600);
    unsigned short* bab  = (unsigned short*)(ws + 17567616);
    unsigned short* bpb  = (unsigned short*)(ws + 17572224);
    unsigned short* q_ws = (unsigned short*)(ws + 17573760);
    unsigned short* k_ws = (unsigned short*)(ws + 30156672);
    unsigned short* v_ws = (unsigned short*)(ws + 42739584);
    unsigned short* att  = x_bf;  // reuse: x_bf dead after gemm_qkv

    detect_dtype<<<1, 256, 0, stream>>>((const unsigned int*)w_attn, flag);
    cast_x<<<6144, 256, 0, stream>>>(x, x_bf, flag);
    cast_small<<<524, 256, 0, stream>>>(rel, b_attn, b_proj, relb, bab, bpb, flag);
    transpose_w<<<dim3(36, 12), 256, 0, stream>>>(w_attn, wTa, 768, 2304, flag);
    transpose_w<<<dim3(12, 12), 256, 0, stream>>>(w_proj, wTp, 768, 768, flag);
    gemm_qkv<<<dim3(32, 18), 256, 0, stream>>>(x_bf, wTa, bab, relb, q_ws, k_ws, v_ws);
    attn_fused<<<768, 256, 0, stream>>>(q_ws, k_ws, v_ws, att);
    gemm_proj<<<dim3(64, 6), 256, 0, stream>>>(att, wTp, bpb, flag, (void*)d_out);
}

// Round 12
// 207.899 us; speedup vs baseline: 1.0999x; 1.0999x over previous
//
#include <hip/hip_runtime.h>
#include <stdint.h>

// Pipeline: detect dtype -> cast inputs to bf16 -> transpose weights ->
//   GEMM1(x @ w_attn^T, scatter Q*scale*log2e / K+rel / V^T) -> flash attention
//   (swapped-QK^T lane-local softmax, log2-domain) -> GEMM2 (+b_proj) -> out
// R12: gemm_qkv reverted to R10 128x128 3-buf counted-vmcnt (R11's 256x128
// regressed: occupancy collapse). attn v7: 512-thread blocks, paired q-tiles
// {15-p, p} run CONCURRENTLY (4 waves each) sharing one K/V staging stream.

typedef __attribute__((ext_vector_type(8))) short short8;
typedef __attribute__((ext_vector_type(4))) float f32x4;
typedef __attribute__((ext_vector_type(4))) unsigned short ushort4v;

#define DEV static __device__ __forceinline__

DEV float bf2f(unsigned short u) {
    union { unsigned int u; float f; } v; v.u = ((unsigned int)u) << 16; return v.f;
}
DEV unsigned short f2bf(float f) {
    union { float f; unsigned int u; } v; v.f = f;
    unsigned int u = v.u;
    return (unsigned short)((u + 0x7fffu + ((u >> 16) & 1u)) >> 16);
}

typedef const __attribute__((address_space(1))) void* gas_ptr;
typedef __attribute__((address_space(3))) void* las_ptr;
DEV void glds16(const void* g, void* l) {
    __builtin_amdgcn_global_load_lds((gas_ptr)g, (las_ptr)l, 16, 0, 0);
}

// ---------------- dtype detector ----------------
__global__ void detect_dtype(const unsigned int* __restrict__ w, int* __restrict__ flag) {
    __shared__ int cnt;
    if (threadIdx.x == 0) cnt = 0;
    __syncthreads();
    int c = 0;
    for (int i = threadIdx.x; i < 8192; i += 256) {
        unsigned int b1 = (w[i] >> 8) & 0x7F;
        c += (b1 >= 0x38 && b1 <= 0x3E) ? 1 : 0;
    }
    atomicAdd(&cnt, c);
    __syncthreads();
    if (threadIdx.x == 0) *flag = (cnt > 4096) ? 1 : 0;  // 1 = bf16 inputs
}

// ---------------- casts ----------------
__global__ __launch_bounds__(256) void cast_x(
    const void* __restrict__ x, unsigned short* __restrict__ xo,
    const int* __restrict__ flag)
{
    int i = (blockIdx.x * 256 + threadIdx.x) * 4;
    if (*flag) {
        *(ushort4v*)(xo + i) = *(const ushort4v*)((const unsigned short*)x + i);
    } else {
        f32x4 v = *(const f32x4*)((const float*)x + i);
        ushort4v o;
#pragma unroll
        for (int j = 0; j < 4; ++j) o[j] = f2bf(v[j]);
        *(ushort4v*)(xo + i) = o;
    }
}

__global__ __launch_bounds__(256) void cast_small(
    const void* __restrict__ rel, const void* __restrict__ ba, const void* __restrict__ bp,
    unsigned short* __restrict__ rel_o, unsigned short* __restrict__ ba_o,
    unsigned short* __restrict__ bp_o, const int* __restrict__ flag)
{
    int i = blockIdx.x * 256 + threadIdx.x;
    if (i >= 134080) return;
    int isbf = *flag;
    const void* src; unsigned short* dst; int off;
    if (i < 131008)      { src = rel; dst = rel_o; off = i; }
    else if (i < 133312) { src = ba;  dst = ba_o;  off = i - 131008; }
    else                 { src = bp;  dst = bp_o;  off = i - 133312; }
    dst[off] = isbf ? ((const unsigned short*)src)[off]
                    : f2bf(((const float*)src)[off]);
}

// ---------------- weight transpose (either dtype in, bf16 out), 64x64 tiles ----
__global__ __launch_bounds__(256) void transpose_w(
    const void* __restrict__ in, unsigned short* __restrict__ out,
    int R, int C, const int* __restrict__ flag)
{
    __shared__ unsigned short tile[64][66];
    const int t = threadIdx.x;
    const int cb = blockIdx.x * 64;
    const int rb = blockIdx.y * 64;
    if (*flag) {
        const unsigned short* inp = (const unsigned short*)in;
        const int c8 = (t & 7) * 8;
        const int r = t >> 3;
#pragma unroll
        for (int p = 0; p < 2; ++p) {
            int rr = r + p * 32;
            short8 v = *(const short8*)(inp + (size_t)(rb + rr) * C + cb + c8);
#pragma unroll
            for (int i = 0; i < 8; ++i) tile[rr][c8 + i] = (unsigned short)v[i];
        }
    } else {
        const float* inp = (const float*)in;
        const int c4 = (t & 15) * 4;
        const int r = t >> 4;
#pragma unroll
        for (int p = 0; p < 4; ++p) {
            int rr = r + p * 16;
            f32x4 v = *(const f32x4*)(inp + (size_t)(rb + rr) * C + cb + c4);
#pragma unroll
            for (int i = 0; i < 4; ++i) tile[rr][c4 + i] = f2bf(v[i]);
        }
    }
    __syncthreads();
    {
        const int c8 = (t & 7) * 8;
        const int r = t >> 3;
#pragma unroll
        for (int p = 0; p < 2; ++p) {
            int oc = r + p * 32;
            short8 v;
#pragma unroll
            for (int i = 0; i < 8; ++i) v[i] = (short)tile[c8 + i][oc];
            *(short8*)(out + (size_t)(cb + oc) * R + rb + c8) = v;
        }
    }
}

// -- GEMM skeleton: 128x128 tile, BK=32, 4 waves, 3-buf + counted vmcnt(4) ----
// (R10 version, measured 49.8us for gemm_qkv)
#define GEMM_STAGE(kk, sl)                                                       \
    glds16(Ab + (size_t)r0 * 768 + (kk) + o0, (char*)Abuf[sl] + lof0);           \
    glds16(Ab + (size_t)r1 * 768 + (kk) + o1, (char*)Abuf[sl] + lof1);           \
    glds16(Bb + (size_t)r0 * 768 + (kk) + o0, (char*)Bbuf[sl] + lof0);           \
    glds16(Bb + (size_t)r1 * 768 + (kk) + o1, (char*)Bbuf[sl] + lof1);

#define GEMM_PROLOG(A_, Bt_)                                                     \
    __shared__ __align__(16) unsigned short Abuf[3][128 * 32];                   \
    __shared__ __align__(16) unsigned short Bbuf[3][128 * 32];                   \
    const int t = threadIdx.x;                                                   \
    const int wave = t >> 6, lane = t & 63;                                      \
    const int lo = lane & 15, hi = lane >> 4;                                    \
    const int wr = wave >> 1, wc = wave & 1;                                     \
    const int bm = blockIdx.x * 128;                                             \
    const int bn = blockIdx.y * 128;                                             \
    int L0 = t << 4, L1 = (t + 256) << 4;                                        \
    int S0 = L0 ^ (((L0 >> 7) & 3) << 4);                                        \
    int S1 = L1 ^ (((L1 >> 7) & 3) << 4);                                        \
    int r0 = S0 >> 6, o0 = (S0 & 63) >> 1;                                       \
    int r1 = S1 >> 6, o1 = (S1 & 63) >> 1;                                       \
    const unsigned short* Ab = (A_) + (size_t)bm * 768;                          \
    const unsigned short* Bb = (Bt_) + (size_t)bn * 768;                         \
    const int lof0 = (wave * 64) << 4;                                           \
    const int lof1 = (256 + wave * 64) << 4;                                     \
    int aoff[4]; int boff[4];                                                    \
    _Pragma("unroll")                                                            \
    for (int m = 0; m < 4; ++m) {                                                \
        int Pa = ((wr * 64 + m * 16 + lo) << 6) + (hi << 4);                     \
        aoff[m] = Pa ^ (((Pa >> 7) & 3) << 4);                                   \
        int Pb = ((wc * 64 + m * 16 + lo) << 6) + (hi << 4);                     \
        boff[m] = Pb ^ (((Pb >> 7) & 3) << 4);                                   \
    }                                                                            \
    f32x4 acc[4][4];                                                             \
    _Pragma("unroll")                                                            \
    for (int m = 0; m < 4; ++m)                                                  \
        _Pragma("unroll")                                                        \
        for (int n = 0; n < 4; ++n) acc[m][n] = (f32x4){0.f, 0.f, 0.f, 0.f};     \
    GEMM_STAGE(0, 0)                                                             \
    GEMM_STAGE(32, 1)                                                            \
    _Pragma("unroll")                                                            \
    for (int kt_ = 0; kt_ < 24; ++kt_) {                                         \
        if (kt_ < 23) { asm volatile("s_waitcnt vmcnt(4)" ::: "memory"); }       \
        else          { asm volatile("s_waitcnt vmcnt(0)" ::: "memory"); }       \
        __builtin_amdgcn_s_barrier();                                            \
        if (kt_ + 2 < 24) { GEMM_STAGE((kt_ + 2) * 32, (kt_ + 2) % 3) }          \
        const int cur_ = kt_ % 3;                                                \
        short8 af[4], bfv[4];                                                    \
        _Pragma("unroll")                                                        \
        for (int m = 0; m < 4; ++m)                                              \
            af[m] = *(const short8*)((const char*)Abuf[cur_] + aoff[m]);         \
        _Pragma("unroll")                                                        \
        for (int n = 0; n < 4; ++n)                                              \
            bfv[n] = *(const short8*)((const char*)Bbuf[cur_] + boff[n]);        \
        _Pragma("unroll")                                                        \
        for (int m = 0; m < 4; ++m)                                              \
            _Pragma("unroll")                                                    \
            for (int n = 0; n < 4; ++n)                                          \
                acc[m][n] = __builtin_amdgcn_mfma_f32_16x16x32_bf16(             \
                    af[m], bfv[n], acc[m][n], 0, 0, 0);                          \
    }

// GEMM1: epilogue scatters q (scale*log2e folded), k (+rel), v (transposed)
__global__ __launch_bounds__(256) void gemm_qkv(
    const unsigned short* __restrict__ A,
    const unsigned short* __restrict__ Bt,
    const unsigned short* __restrict__ bias,
    const unsigned short* __restrict__ rel,
    unsigned short* __restrict__ q_ws,
    unsigned short* __restrict__ k_ws,
    unsigned short* __restrict__ v_ws)
{
    GEMM_PROLOG(A, Bt)
    const int gm0 = bm + wr * 64 + hi * 4;
    const float QSCALE = 0.125f * 1.44269504f;  // fold log2e
#pragma unroll
    for (int m = 0; m < 4; ++m) {
        int gm = gm0 + m * 16;
        int b_ = gm >> 10;
        int tt = gm & 1023;
#pragma unroll
        for (int n = 0; n < 4; ++n) {
            int col = bn + wc * 64 + n * 16 + lo;
            float bs = bf2f(bias[col]);
            if (col < 768) {
                int h = col >> 6, d = col & 63;
                size_t base = (((size_t)b_ * 12 + h) * 1024 + tt) * 64 + d;
#pragma unroll
                for (int j = 0; j < 4; ++j)
                    q_ws[base + (size_t)j * 64] = f2bf((acc[m][n][j] + bs) * QSCALE);
            } else if (col < 1536) {
                int h = (col - 768) >> 6, d = col & 63;
                size_t base = (((size_t)b_ * 12 + h) * 1024 + tt) * 64 + d;
#pragma unroll
                for (int j = 0; j < 4; ++j) {
                    int trow = tt + j;
                    float rv = (trow > 0) ? bf2f(rel[(size_t)(trow - 1) * 64 + d]) : 0.f;
                    k_ws[base + (size_t)j * 64] = f2bf(acc[m][n][j] + bs + rv);
                }
            } else {
                int h = (col - 1536) >> 6, d = col & 63;
                size_t vb = (((size_t)b_ * 12 + h) * 64 + d) * 1024 + tt;
                ushort4v pk;
#pragma unroll
                for (int j = 0; j < 4; ++j) pk[j] = f2bf(acc[m][n][j] + bs);
                *(ushort4v*)(v_ws + vb) = pk;
            }
        }
    }
}

// GEMM2: att @ wT_proj + b_proj -> out (dtype per flag)
__global__ __launch_bounds__(256) void gemm_proj(
    const unsigned short* __restrict__ A,
    const unsigned short* __restrict__ Bt,
    const unsigned short* __restrict__ bias,
    const int* __restrict__ flag,
    void* __restrict__ outv)
{
    GEMM_PROLOG(A, Bt)
    const int isbf = *flag;
    const int gm0 = bm + wr * 64 + hi * 4;
#pragma unroll
    for (int m = 0; m < 4; ++m) {
        int gm = gm0 + m * 16;
#pragma unroll
        for (int n = 0; n < 4; ++n) {
            int col = bn + wc * 64 + n * 16 + lo;
            float bs = bf2f(bias[col]);
#pragma unroll
            for (int j = 0; j < 4; ++j) {
                float v = acc[m][n][j] + bs;
                if (isbf)
                    ((unsigned short*)outv)[(size_t)(gm + j) * 768 + col] = f2bf(v);
                else
                    ((float*)outv)[(size_t)(gm + j) * 768 + col] = v;
            }
        }
    }
}

// ---- flash attention v7: 512 threads, paired q-tiles run concurrently -------
// Waves 0-3 -> qt = 15-p (heavy), waves 4-7 -> qt = p (light). One K/V staging
// stream of nkt_max = 16-p tiles serves all 8 waves (light waves skip compute
// after their range but keep hitting barriers). LDS 48KB -> 3 blocks/CU
// -> 24 waves/CU. Swapped-QK^T lane-local softmax, log2 domain (v6 body).
__global__ __launch_bounds__(512) void attn_fused(
    const unsigned short* __restrict__ q_ws,
    const unsigned short* __restrict__ k_ws,
    const unsigned short* __restrict__ v_ws,
    unsigned short* __restrict__ att)
{
    __shared__ __align__(16) unsigned short Kbuf[2][64 * 64];
    __shared__ __align__(16) unsigned short Vbuf[2][64 * 64];
    __shared__ __align__(16) unsigned short Pbuf[8][16 * 64];
    const int t = threadIdx.x;            // 0..511
    const int wave = t >> 6, lane = t & 63;
    const int lo = lane & 15, hi = lane >> 4;
    const int gid = blockIdx.x;
    const int xcd = gid & 7;
    const int c = gid >> 3;               // 0..95
    const int bh = xcd * 12 + (c % 12);
    const int p = c / 12;                 // 0..7
    const int b_ = bh / 12, h = bh % 12;
    const size_t base = (size_t)bh * (1024 * 64);
    const unsigned short* Kb = k_ws + base;
    const unsigned short* Vb = v_ws + base;
    const float DEFER_THR = 11.5f;        // ~8 nats in log2 units

    const int qt = (wave < 4) ? (15 - p) : p;
    const int nkt = qt + 1;               // this wave's KV-tile count
    const int nkt_max = 16 - p;           // block loop bound (heavy half)
    const int q0w = qt * 64 + (wave & 3) * 16;
    const int qrow = q0w + lo;

    // staging: 512 threads x 16B = 8KB tile; per-lane source pre-swizzled,
    // wave-uniform LDS dest (wave*1024)
    int L0 = t << 4;
    int S0 = L0 ^ (((L0 >> 7) & 7) << 4);
    int r0 = S0 >> 7, o0 = (S0 & 127) >> 1;
    const int lofK = (wave * 64) << 4;

    int koff[4][2];
#pragma unroll
    for (int nt = 0; nt < 4; ++nt)
#pragma unroll
        for (int kc = 0; kc < 2; ++kc) {
            int P = ((nt * 16 + lo) << 7) + (kc << 6) + (hi << 4);
            koff[nt][kc] = P ^ (((P >> 7) & 7) << 4);
        }
    int poffR[2];
#pragma unroll
    for (int kc = 0; kc < 2; ++kc) {
        int P = (lo << 7) + (kc << 6) + (hi << 4);
        poffR[kc] = P ^ (((P >> 7) & 7) << 4);
    }
    int poffW[4][4];
#pragma unroll
    for (int nt = 0; nt < 4; ++nt)
#pragma unroll
        for (int j = 0; j < 4; ++j) {
            int P = (lo << 7) + ((nt * 16 + hi * 4 + j) << 1);
            poffW[nt][j] = P ^ ((lo & 7) << 4);
        }
    char* pb = (char*)&Pbuf[wave][0];

    short8 qf[2];
#pragma unroll
    for (int kc = 0; kc < 2; ++kc)
        qf[kc] = *(const short8*)(q_ws + base +
            (size_t)(q0w + lo) * 64 + kc * 32 + hi * 8);

    f32x4 o[4];
    float mrun = -1e30f, lrun = 0.f;
#pragma unroll
    for (int nt = 0; nt < 4; ++nt) o[nt] = (f32x4){0.f, 0.f, 0.f, 0.f};

    // prologue: stage tile 0
    glds16(Kb + (size_t)r0 * 64 + o0, (char*)Kbuf[0] + lofK);
    glds16(Vb + (size_t)r0 * 1024 + o0, (char*)Vbuf[0] + lofK);

    int cur = 0;
    for (int kt = 0; kt < nkt_max; ++kt) {
        __syncthreads();  // staging of tile kt complete
        if (kt + 1 < nkt_max) {
            const int kn = (kt + 1) * 64;
            glds16(Kb + (size_t)(kn + r0) * 64 + o0, (char*)Kbuf[cur ^ 1] + lofK);
            glds16(Vb + (size_t)r0 * 1024 + kn + o0, (char*)Vbuf[cur ^ 1] + lofK);
        }
        if (kt < nkt) {
            const int kv0 = kt * 64;
            const char* Kc = (const char*)Kbuf[cur];
            const char* Vc = (const char*)Vbuf[cur];

            short8 kf[4][2];
#pragma unroll
            for (int nt = 0; nt < 4; ++nt)
#pragma unroll
                for (int kc = 0; kc < 2; ++kc)
                    kf[nt][kc] = *(const short8*)(Kc + koff[nt][kc]);
            // swapped: A=K, B=Q -> sc[nt] col=q(lo), rows=kv(hi*4+j)
            f32x4 sc[4];
            __builtin_amdgcn_s_setprio(1);
#pragma unroll
            for (int nt = 0; nt < 4; ++nt) {
                f32x4 z = (f32x4){0.f, 0.f, 0.f, 0.f};
                z = __builtin_amdgcn_mfma_f32_16x16x32_bf16(kf[nt][0], qf[0], z, 0, 0, 0);
                z = __builtin_amdgcn_mfma_f32_16x16x32_bf16(kf[nt][1], qf[1], z, 0, 0, 0);
                sc[nt] = z;
            }
            __builtin_amdgcn_s_setprio(0);
            if (kv0 + 63 > q0w) {
#pragma unroll
                for (int nt = 0; nt < 4; ++nt)
#pragma unroll
                    for (int j = 0; j < 4; ++j) {
                        int kc_ = kv0 + nt * 16 + hi * 4 + j;
                        if (kc_ > qrow) sc[nt][j] = -1e30f;
                    }
            }
            // lane-local row max (15 VALU) + 2 shfl across hi-groups
            float m0;
            {
                float a0 = fmaxf(fmaxf(sc[0][0], sc[0][1]), fmaxf(sc[0][2], sc[0][3]));
                float a1 = fmaxf(fmaxf(sc[1][0], sc[1][1]), fmaxf(sc[1][2], sc[1][3]));
                float a2 = fmaxf(fmaxf(sc[2][0], sc[2][1]), fmaxf(sc[2][2], sc[2][3]));
                float a3 = fmaxf(fmaxf(sc[3][0], sc[3][1]), fmaxf(sc[3][2], sc[3][3]));
                m0 = fmaxf(fmaxf(a0, a1), fmaxf(a2, a3));
            }
            m0 = fmaxf(m0, __shfl_xor(m0, 16));
            m0 = fmaxf(m0, __shfl_xor(m0, 32));
            // defer-max rescale
            if (__any(m0 > mrun + DEFER_THR)) {
                float nm = fmaxf(mrun, m0);
                float corr = __builtin_amdgcn_exp2f(mrun - nm);
                mrun = nm;
                lrun *= corr;
#pragma unroll
                for (int j = 0; j < 4; ++j) {
                    float cj = __shfl(corr, hi * 4 + j);
#pragma unroll
                    for (int nt = 0; nt < 4; ++nt) o[nt][j] *= cj;
                }
            }
            // exp2 + lane-local sum + 2 shfl
            float rs = 0.f;
#pragma unroll
            for (int nt = 0; nt < 4; ++nt)
#pragma unroll
                for (int j = 0; j < 4; ++j) {
                    float pv = __builtin_amdgcn_exp2f(sc[nt][j] - mrun);
                    sc[nt][j] = pv;
                    rs += pv;
                }
            rs += __shfl_xor(rs, 16);
            rs += __shfl_xor(rs, 32);
            lrun += rs;
            // V fragments (hoisted)
            short8 vf[4][2];
#pragma unroll
            for (int nt = 0; nt < 4; ++nt)
#pragma unroll
                for (int kc2 = 0; kc2 < 2; ++kc2)
                    vf[nt][kc2] = *(const short8*)(Vc + koff[nt][kc2]);
            // P -> LDS (row = lo = q-row), wave-private
#pragma unroll
            for (int nt = 0; nt < 4; ++nt)
#pragma unroll
                for (int j = 0; j < 4; ++j)
                    *(unsigned short*)(pb + poffW[nt][j]) = f2bf(sc[nt][j]);
            // PV
#pragma unroll
            for (int kc2 = 0; kc2 < 2; ++kc2) {
                short8 pf = *(const short8*)(pb + poffR[kc2]);
                __builtin_amdgcn_s_setprio(1);
#pragma unroll
                for (int nt = 0; nt < 4; ++nt)
                    o[nt] = __builtin_amdgcn_mfma_f32_16x16x32_bf16(pf, vf[nt][kc2], o[nt], 0, 0, 0);
                __builtin_amdgcn_s_setprio(0);
            }
        }
        cur ^= 1;
    }
    // epilogue: lrun for row hi*4+j lives at lane (hi*4+j)
#pragma unroll
    for (int j = 0; j < 4; ++j) {
        float lj = __shfl(lrun, hi * 4 + j);
        float inv = 1.f / lj;
        int tt = q0w + hi * 4 + j;
#pragma unroll
        for (int nt = 0; nt < 4; ++nt)
            att[((size_t)(b_ * 1024 + tt)) * 768 + h * 64 + nt * 16 + lo] =
                f2bf(o[nt][j] * inv);
    }
}

extern "C" void kernel_launch(void* const* d_in, const int* in_sizes, int n_in,
                              void* d_out, int out_size, void* d_ws, size_t ws_size,
                              hipStream_t stream) {
    const void* x      = d_in[0];
    const void* w_attn = d_in[1];
    const void* b_attn = d_in[2];
    const void* w_proj = d_in[3];
    const void* b_proj = d_in[4];
    const void* rel    = d_in[5];
    char* ws = (char*)d_ws;
    int*            flag = (int*)(ws + 0);
    unsigned short* wTa  = (unsigned short*)(ws + 4096);
    unsigned short* wTp  = (unsigned short*)(ws + 3543040);
    unsigned short* x_bf = (unsigned short*)(ws + 4722688);
    unsigned short* relb = (unsigned short*)(ws + 17305600);
    unsigned short* bab  = (unsigned short*)(ws + 17567616);
    unsigned short* bpb  = (unsigned short*)(ws + 17572224);
    unsigned short* q_ws = (unsigned short*)(ws + 17573760);
    unsigned short* k_ws = (unsigned short*)(ws + 30156672);
    unsigned short* v_ws = (unsigned short*)(ws + 42739584);
    unsigned short* att  = x_bf;  // reuse: x_bf dead after gemm_qkv

    detect_dtype<<<1, 256, 0, stream>>>((const unsigned int*)w_attn, flag);
    cast_x<<<6144, 256, 0, stream>>>(x, x_bf, flag);
    cast_small<<<524, 256, 0, stream>>>(rel, b_attn, b_proj, relb, bab, bpb, flag);
    transpose_w<<<dim3(36, 12), 256, 0, stream>>>(w_attn, wTa, 768, 2304, flag);
    transpose_w<<<dim3(12, 12), 256, 0, stream>>>(w_proj, wTp, 768, 768, flag);
    gemm_qkv<<<dim3(64, 18), 256, 0, stream>>>(x_bf, wTa, bab, relb, q_ws, k_ws, v_ws);
    attn_fused<<<768, 512, 0, stream>>>(q_ws, k_ws, v_ws, att);
    gemm_proj<<<dim3(64, 6), 256, 0, stream>>>(att, wTp, bpb, flag, (void*)d_out);
}